// Round 12
// baseline (244.457 us; speedup 1.0000x reference)
//
#include <hip/hip_runtime.h>

typedef unsigned short u16;
typedef unsigned int u32;
typedef __attribute__((ext_vector_type(8))) __bf16 bf8v;    // MFMA A/B operand (8 bf16)
typedef __attribute__((ext_vector_type(8))) short s8v;      // same bits, for packing
typedef __attribute__((ext_vector_type(4))) float f4v;
typedef __attribute__((ext_vector_type(16))) float f16v;    // 32x32 MFMA C/D

#define DEV static __device__ __forceinline__

constexpr int NQ = 12544;   // B*H*W = 16*28*28
constexpr int MM = 8192;    // memory bank rows
constexpr int PP = 784;     // H*W
constexpr float EPSF = 1e-12f;

DEV u16 f2bf(float f) {  // RNE f32 -> bf16 (inputs are finite normals)
  u32 u = __float_as_uint(f);
  return (u16)((u + 0x7FFFu + ((u >> 16) & 1u)) >> 16);
}
DEV float bf2f(u16 h) { return __uint_as_float((u32)h << 16); }

DEV void gl2lds16(const u16* g, u16* l) {
  __builtin_amdgcn_global_load_lds(
      (const __attribute__((address_space(1))) unsigned int*)(g),
      (__attribute__((address_space(3))) unsigned int*)(l), 16, 0, 0);
}

// branchless sorted insert: keep 5 smallest in a0<=..<=a4
DEV void ins5(float v, float& a0, float& a1, float& a2, float& a3, float& a4) {
  float hi;
  hi = fmaxf(v, a0); a0 = fminf(v, a0); v = hi;
  hi = fmaxf(v, a1); a1 = fminf(v, a1); v = hi;
  hi = fmaxf(v, a2); a2 = fminf(v, a2); v = hi;
  hi = fmaxf(v, a3); a3 = fminf(v, a3); v = hi;
  a4 = fminf(v, a4);
}

// ================= fused prep =================
DEV void pack_bf16_dev(const float* __restrict__ x, u16* __restrict__ y, int bid, int tid) {
  int g = bid * 256 + tid;
  const float4* px = (const float4*)x + (size_t)g * 2;
  float4 a = px[0], b = px[1];
  s8v o;
  o[0] = (short)f2bf(a.x); o[1] = (short)f2bf(a.y); o[2] = (short)f2bf(a.z); o[3] = (short)f2bf(a.w);
  o[4] = (short)f2bf(b.x); o[5] = (short)f2bf(b.y); o[6] = (short)f2bf(b.z); o[7] = (short)f2bf(b.w);
  ((s8v*)y)[g] = o;
}

// mem pack: store -2*m (exact bf16 scale) K-MAJOR in global: yT[chunk][row][8]
template<int C>
DEV void pack_mem_dev(const float* __restrict__ x, u16* __restrict__ yT, float* __restrict__ nrm,
                      int bid, int tid) {
  int row = bid * 4 + (tid >> 6), lane = tid & 63;
  constexpr int E = C / 64;
  const float* src = x + (size_t)row * C + lane * E;
  float s = 0.f;
  if constexpr (E == 4) {
    float4 v = *(const float4*)src;
    s = v.x * v.x + v.y * v.y + v.z * v.z + v.w * v.w;
    u32 lo = (u32)f2bf(-2.f * v.x) | ((u32)f2bf(-2.f * v.y) << 16);
    u32 hi = (u32)f2bf(-2.f * v.z) | ((u32)f2bf(-2.f * v.w) << 16);
    size_t di = ((size_t)(lane >> 1) * MM + row) * 8 + (lane & 1) * 4;
    *(uint2*)(yT + di) = make_uint2(lo, hi);
  } else {
    float2 v = *(const float2*)src;
    s = v.x * v.x + v.y * v.y;
    size_t di = ((size_t)(lane >> 2) * MM + row) * 8 + (lane & 3) * 2;
    *(u32*)(yT + di) = (u32)f2bf(-2.f * v.x) | ((u32)f2bf(-2.f * v.y) << 16);
  }
#pragma unroll
  for (int m = 1; m < 64; m <<= 1) s += __shfl_xor(s, m);
  if (lane == 0) nrm[row] = s;
}

template<int C>
DEV void pack_q_dev(const float* __restrict__ q, u16* __restrict__ qfb, int bid, int tid) {
  int g = bid * 256 + tid;
  int n = g % NQ;
  int cc = g / NQ;
  int b = n / PP, p = n % PP;
  int c0 = cc * 8;
  const float* src = q + ((size_t)b * C + c0) * PP + p;
  s8v o;
#pragma unroll
  for (int i = 0; i < 8; ++i) o[i] = (short)f2bf(src[(size_t)i * PP]);
  ((s8v*)qfb)[((size_t)n * C + c0) >> 3] = o;
}

__global__ __launch_bounds__(256) void k_prep(
    const float* __restrict__ q2, const float* __restrict__ q3,
    const float* __restrict__ mem2, const float* __restrict__ mem3,
    const float* __restrict__ icov2, const float* __restrict__ icov3,
    u16* __restrict__ qf2b, u16* __restrict__ qf3b,
    u16* __restrict__ m2t, u16* __restrict__ m3t,
    u16* __restrict__ ic2b, u16* __restrict__ ic3b,
    float* __restrict__ mn2, float* __restrict__ mn3) {
  int bid = blockIdx.x, tid = threadIdx.x;
  if (bid < 2048)       pack_mem_dev<128>(mem2, m2t, mn2, bid, tid);
  else if (bid < 4096)  pack_mem_dev<256>(mem3, m3t, mn3, bid - 2048, tid);
  else if (bid < 4104)  pack_bf16_dev(icov2, ic2b, bid - 4096, tid);
  else if (bid < 4136)  pack_bf16_dev(icov3, ic3b, bid - 4104, tid);
  else if (bid < 4920)  pack_q_dev<128>(q2, qf2b, bid - 4136, tid);
  else                  pack_q_dev<256>(q3, qf3b, bid - 4920, tid);
}

// ================= fused distances + per-row 5 smallest d2' =================
// R12 structure: ONE barrier per block (R6-R11 lesson: ~2us fixed cost per
// tile-barrier-round was the invariant wall). NSPLIT=32 -> the whole 256-row
// mem slice fits in LDS (128KB @C=256); stage once, sync once, then each wave
// runs 8 inner tiles of pure {ds_read -> 32x32x16 MFMA -> in-reg top-5} with
// ZERO barriers. CG q-col-groups per wave (CG=2 @C=256 halves LDS-read/FLOP).
template<int C, int CG, int NSPLIT, int WPEU>
__global__ __launch_bounds__(512, WPEU)
void k_score(const u16* __restrict__ qf, const u16* __restrict__ memT,
             const float* __restrict__ mn, float* __restrict__ kp) {
  constexpr int MS = MM / NSPLIT;          // 256 mem rows per block
  constexpr int CHUNKS = C / 8;            // 16B chunks per row (32 / 16)
  constexpr int NTI = MS / 32;             // 8 inner tiles
  constexpr int UNITS = MS * CHUNKS;       // 16B units in slice (8192 / 4096)
  constexpr int TSH = (CHUNKS == 32) ? 10 : 9;   // log2(CHUNKS*32)
  constexpr int QROWS = 8 * 32 * CG;       // q rows per block (512 / 256)
  __shared__ alignas(16) u16 Bs[UNITS * 8];       // [t][chunk][row32][8]
  __shared__ alignas(16) float mnS[MS];

  const int tid = threadIdx.x, wave = tid >> 6, lane = tid & 63;
  const int l31 = lane & 31, kh = lane >> 5;
  const int rt = blockIdx.x / NSPLIT, split = blockIdx.x % NSPLIT;
  const int row0 = rt * QROWS, mb0 = split * MS;

  // q fragments (B operand; loop-invariant) -> registers, pinned.
  bf8v qv[CG][C / 16];
#pragma unroll
  for (int cg = 0; cg < CG; ++cg)
#pragma unroll
    for (int kk = 0; kk < C / 16; ++kk)
      qv[cg][kk] = *(const bf8v*)(qf + (size_t)(row0 + wave * 32 * CG + cg * 32 + l31) * C + kk * 16 + kh * 8);
#pragma unroll
  for (int cg = 0; cg < CG; ++cg)
#pragma unroll
    for (int kk = 0; kk < C / 16; ++kk)
      asm volatile("" : "+v"(qv[cg][kk]));

  // stage the WHOLE slice once (coalesced: 64 consecutive rows per wave-iter)
#pragma unroll
  for (int it = 0; it < UNITS / 512; ++it) {
    int U = it * 512 + tid;
    int t = U >> TSH;
    int cp = (U >> 5) & (CHUNKS - 1);
    int r = U & 31;
    gl2lds16(memT + ((size_t)cp * MM + mb0 + t * 32 + r) * 8, Bs + (size_t)U * 8);
  }
  if (tid < 64) gl2lds16((const u16*)(mn + mb0) + tid * 8, (u16*)mnS + tid * 8);
  __syncthreads();   // THE one barrier: slice + norms resident

  float t5[CG][5];
#pragma unroll
  for (int cg = 0; cg < CG; ++cg)
#pragma unroll
    for (int i = 0; i < 5; ++i) t5[cg][i] = 1e30f;

  const u16* baseA = Bs + l31 * 8 + kh * 256;   // + t*(CHUNKS*256) + kk*512 (u16)
#pragma unroll
  for (int t = 0; t < NTI; ++t) {
    const u16* Bt = baseA + t * (CHUNKS * 256);
    f16v acc[CG];
#pragma unroll
    for (int g = 0; g < 4; ++g) {
      f4v m4 = *(const f4v*)(mnS + t * 32 + g * 8 + kh * 4);
#pragma unroll
      for (int cg = 0; cg < CG; ++cg) {
        acc[cg][4 * g + 0] = m4[0]; acc[cg][4 * g + 1] = m4[1];
        acc[cg][4 * g + 2] = m4[2]; acc[cg][4 * g + 3] = m4[3];
      }
    }
#pragma unroll
    for (int kk = 0; kk < C / 16; ++kk) {
      bf8v mf = *(const bf8v*)(Bt + kk * 512);
#pragma unroll
      for (int cg = 0; cg < CG; ++cg)
        acc[cg] = __builtin_amdgcn_mfma_f32_32x32x16_bf16(mf, qv[cg][kk], acc[cg], 0, 0, 0);
    }
#pragma unroll
    for (int cg = 0; cg < CG; ++cg)
#pragma unroll
      for (int g = 0; g < 4; ++g) {
        float c0 = acc[cg][4 * g + 0], c1 = acc[cg][4 * g + 1];
        float c2 = acc[cg][4 * g + 2], c3 = acc[cg][4 * g + 3];
        float m01 = fminf(fminf(c0, c1), fminf(c2, c3));
        if (m01 < t5[cg][4]) {
          ins5(c0, t5[cg][0], t5[cg][1], t5[cg][2], t5[cg][3], t5[cg][4]);
          ins5(c1, t5[cg][0], t5[cg][1], t5[cg][2], t5[cg][3], t5[cg][4]);
          ins5(c2, t5[cg][0], t5[cg][1], t5[cg][2], t5[cg][3], t5[cg][4]);
          ins5(c3, t5[cg][0], t5[cg][1], t5[cg][2], t5[cg][3], t5[cg][4]);
        }
      }
  }

  // merge the 2 lanes holding the same q-col (lane, lane+32), write (guarded: q-row padding)
#pragma unroll
  for (int cg = 0; cg < CG; ++cg) {
    float r0 = __shfl_xor(t5[cg][0], 32), r1 = __shfl_xor(t5[cg][1], 32),
          r2 = __shfl_xor(t5[cg][2], 32), r3 = __shfl_xor(t5[cg][3], 32),
          r4 = __shfl_xor(t5[cg][4], 32);
    ins5(r0, t5[cg][0], t5[cg][1], t5[cg][2], t5[cg][3], t5[cg][4]);
    ins5(r1, t5[cg][0], t5[cg][1], t5[cg][2], t5[cg][3], t5[cg][4]);
    ins5(r2, t5[cg][0], t5[cg][1], t5[cg][2], t5[cg][3], t5[cg][4]);
    ins5(r3, t5[cg][0], t5[cg][1], t5[cg][2], t5[cg][3], t5[cg][4]);
    ins5(r4, t5[cg][0], t5[cg][1], t5[cg][2], t5[cg][3], t5[cg][4]);
    if (lane < 32) {
      int grow = row0 + wave * 32 * CG + cg * 32 + l31;
      if (grow < NQ) {
        float* o = kp + ((size_t)grow * NSPLIT + split) * 5;
        o[0] = t5[cg][0]; o[1] = t5[cg][1]; o[2] = t5[cg][2]; o[3] = t5[cg][3]; o[4] = t5[cg][4];
      }
    }
  }
}

// ================= fused mid: q row-norms + Mahalanobis =================
template<int C>
DEV void rownorm_dev(const u16* __restrict__ x, float* __restrict__ out, int bid, int tid) {
  int row = bid * 4 + (tid >> 6);
  int lane = tid & 63;
  constexpr int E = C / 64;
  const u16* p = x + (size_t)row * C + lane * E;
  float s = 0.f;
#pragma unroll
  for (int i = 0; i < E; ++i) { float v = bf2f(p[i]); s += v * v; }
#pragma unroll
  for (int m = 1; m < 64; m <<= 1) s += __shfl_xor(s, m);
  if (lane == 0) out[row] = s;
}

template<int C>
DEV void maha_dev(const u16* __restrict__ qfb, const float* __restrict__ mu,
                  const u16* __restrict__ icovb, float* __restrict__ mh,
                  u16* As, float* muS, int bid, int tid) {
  constexpr int QT = 64, KCH = C / 8;
  int wave = tid >> 6, lane = tid & 63;
  int row0 = bid * QT;

  for (int i = tid; i < C; i += 256) muS[i] = mu[i];
  __syncthreads();
  for (int u = tid; u < QT * KCH; u += 256) {
    int r = u / KCH, cc = u % KCH;
    bf8v v = *(const bf8v*)(qfb + (size_t)(row0 + r) * C + cc * 8);
    s8v d;
#pragma unroll
    for (int i = 0; i < 8; ++i) d[i] = (short)f2bf((float)v[i] - muS[cc * 8 + i]);
    *(s8v*)(As + r * C + ((cc ^ (r & 7)) << 3)) = d;
  }
  __syncthreads();

  int arow = wave * 16 + (lane & 15);
  int kb = lane >> 4;
  float mm[4] = {0.f, 0.f, 0.f, 0.f};
#pragma unroll
  for (int cb = 0; cb < C / 16; ++cb) {
    f4v acc = (f4v){0.f, 0.f, 0.f, 0.f};
    int bcol = cb * 16 + (lane & 15);
#pragma unroll
    for (int kk = 0; kk < C / 32; ++kk) {
      int kc = kk * 4 + kb;
      bf8v a = *(const bf8v*)(As + arow * C + ((kc ^ (arow & 7)) << 3));
      bf8v b = *(const bf8v*)(icovb + (size_t)bcol * C + kc * 8);
      acc = __builtin_amdgcn_mfma_f32_16x16x32_bf16(a, b, acc, 0, 0, 0);
    }
#pragma unroll
    for (int r = 0; r < 4; ++r) {
      int row = wave * 16 + (lane >> 4) * 4 + r;
      int col = cb * 16 + (lane & 15);
      float dv = bf2f(As[row * C + (((col >> 3) ^ (row & 7)) << 3) + (col & 7)]);
      mm[r] += acc[r] * dv;
    }
  }
#pragma unroll
  for (int r = 0; r < 4; ++r) {
    float v = mm[r];
    v += __shfl_xor(v, 1); v += __shfl_xor(v, 2);
    v += __shfl_xor(v, 4); v += __shfl_xor(v, 8);
    if ((lane & 15) == 0)
      mh[row0 + wave * 16 + (lane >> 4) * 4 + r] = sqrtf(fmaxf(v, EPSF));
  }
}

__global__ __launch_bounds__(256) void k_mid(
    const u16* __restrict__ qf2b, const u16* __restrict__ qf3b,
    const float* __restrict__ mean2, const float* __restrict__ mean3,
    const u16* __restrict__ ic2b, const u16* __restrict__ ic3b,
    float* __restrict__ qn2, float* __restrict__ qn3,
    float* __restrict__ mh2, float* __restrict__ mh3) {
  __shared__ alignas(16) u16 As[64 * 256];
  __shared__ float muS[256];
  int bid = blockIdx.x, tid = threadIdx.x;
  if (bid < 3136)       rownorm_dev<128>(qf2b, qn2, bid, tid);
  else if (bid < 6272)  rownorm_dev<256>(qf3b, qn3, bid - 3136, tid);
  else if (bid < 6468)  maha_dev<128>(qf2b, mean2, ic2b, mh2, As, muS, bid - 6272, tid);
  else                  maha_dev<256>(qf3b, mean3, ic3b, mh3, As, muS, bid - 6468, tid);
}

// ================= combine: merge knn splits (+qn), build maps =================
template<int S>
DEV float knn_merge(const float* kp, int n, float qv) {
  float t0 = 1e30f, t1 = 1e30f, t2 = 1e30f, t3 = 1e30f, t4 = 1e30f;
  const float* p = kp + (size_t)n * S * 5;
#pragma unroll
  for (int i = 0; i < S * 5; ++i) ins5(p[i], t0, t1, t2, t3, t4);
  return 0.2f * (sqrtf(fmaxf(t0 + qv, EPSF)) + sqrtf(fmaxf(t1 + qv, EPSF)) +
                 sqrtf(fmaxf(t2 + qv, EPSF)) + sqrtf(fmaxf(t3 + qv, EPSF)) +
                 sqrtf(fmaxf(t4 + qv, EPSF)));
}

__global__ __launch_bounds__(256) void k_combine(
    const float* __restrict__ kp2, const float* __restrict__ kp3,
    const float* __restrict__ qn2, const float* __restrict__ qn3,
    const float* __restrict__ mh2, const float* __restrict__ mh3,
    float* __restrict__ out) {
  int n = blockIdx.x * 256 + threadIdx.x;
  float m2v = 0.5f * (knn_merge<32>(kp2, n, qn2[n]) + mh2[n]);
  float m3v = 0.5f * (knn_merge<32>(kp3, n, qn3[n]) + mh3[n]);
  out[16 + n] = 0.5f * (m2v + m3v);
  out[16 + NQ + n] = m2v;
  out[16 + 2 * NQ + n] = m3v;
}

// ================= per-image top-10 mean over 784-pixel map =================
__global__ __launch_bounds__(256) void k_top10(const float* __restrict__ comb, float* __restrict__ pred) {
  __shared__ float vals[1024];
  __shared__ float rv[256];
  __shared__ int ri[256];
  __shared__ float ssum;
  int b = blockIdx.x, tid = threadIdx.x;
  for (int i = tid; i < 1024; i += 256) vals[i] = (i < PP) ? comb[b * PP + i] : -1e30f;
  if (tid == 0) ssum = 0.f;
  __syncthreads();
  for (int it = 0; it < 10; ++it) {
    float bv = -1e30f; int bi = 0;
    for (int i = tid; i < 1024; i += 256) { float v = vals[i]; if (v > bv) { bv = v; bi = i; } }
    rv[tid] = bv; ri[tid] = bi;
    __syncthreads();
    for (int s = 128; s; s >>= 1) {
      if (tid < s && rv[tid + s] > rv[tid]) { rv[tid] = rv[tid + s]; ri[tid] = ri[tid + s]; }
      __syncthreads();
    }
    if (tid == 0) { ssum += rv[0]; vals[ri[0]] = -1e30f; }
    __syncthreads();
  }
  if (tid == 0) pred[b] = ssum * 0.1f;
}

extern "C" void kernel_launch(void* const* d_in, const int* in_sizes, int n_in,
                              void* d_out, int out_size, void* d_ws, size_t ws_size,
                              hipStream_t stream) {
  const float* q2    = (const float*)d_in[0];
  const float* q3    = (const float*)d_in[1];
  const float* mem2  = (const float*)d_in[2];
  const float* mem3  = (const float*)d_in[3];
  const float* mean2 = (const float*)d_in[4];
  const float* mean3 = (const float*)d_in[5];
  const float* icov2 = (const float*)d_in[6];
  const float* icov3 = (const float*)d_in[7];
  float* out = (float*)d_out;

  char* w = (char*)d_ws;
  auto alloc = [&](size_t bytes) { void* p = (void*)w; w += (bytes + 255) & ~(size_t)255; return p; };
  u16* qf2b = (u16*)alloc((size_t)NQ * 128 * 2);
  u16* qf3b = (u16*)alloc((size_t)12800 * 256 * 2);   // padded to 25*512 rows (C=256 tail waves)
  u16* m2t  = (u16*)alloc((size_t)MM * 128 * 2);
  u16* m3t  = (u16*)alloc((size_t)MM * 256 * 2);
  u16* ic2b = (u16*)alloc((size_t)128 * 128 * 2);
  u16* ic3b = (u16*)alloc((size_t)256 * 256 * 2);
  float* qn2 = (float*)alloc((size_t)NQ * 4);
  float* qn3 = (float*)alloc((size_t)NQ * 4);
  float* mn2 = (float*)alloc((size_t)MM * 4);
  float* mn3 = (float*)alloc((size_t)MM * 4);
  float* kp2 = (float*)alloc((size_t)NQ * 32 * 5 * 4);
  float* kp3 = (float*)alloc((size_t)NQ * 32 * 5 * 4);
  float* mh2 = (float*)alloc((size_t)NQ * 4);
  float* mh3 = (float*)alloc((size_t)NQ * 4);

  k_prep<<<6488, 256, 0, stream>>>(q2, q3, mem2, mem3, icov2, icov3,
                                   qf2b, qf3b, m2t, m3t, ic2b, ic3b, mn2, mn3);

  // C=256: CG=2, 25 rt x 32 splits = 800 blocks, 129KB LDS (1 blk/CU), VGPR~200 (2 w/EU)
  // C=128: CG=1, 49 rt x 32 splits = 1568 blocks, 65KB LDS (2 blk/CU), VGPR<=128 (4 w/EU)
  k_score<256, 2, 32, 2><<<25 * 32, 512, 0, stream>>>(qf3b, m3t, mn3, kp3);
  k_score<128, 1, 32, 4><<<49 * 32, 512, 0, stream>>>(qf2b, m2t, mn2, kp2);

  k_mid<<<6664, 256, 0, stream>>>(qf2b, qf3b, mean2, mean3, ic2b, ic3b, qn2, qn3, mh2, mh3);

  k_combine<<<NQ / 256, 256, 0, stream>>>(kp2, kp3, qn2, qn3, mh2, mh3, out);
  k_top10<<<16, 256, 0, stream>>>(out + 16, out);

  (void)in_sizes; (void)n_in; (void)out_size; (void)ws_size;
}

// Round 13
// 211.919 us; speedup vs baseline: 1.1535x; 1.1535x over previous
//
#include <hip/hip_runtime.h>

typedef unsigned short u16;
typedef unsigned int u32;
typedef __attribute__((ext_vector_type(8))) __bf16 bf8v;    // MFMA A/B operand (8 bf16)
typedef __attribute__((ext_vector_type(8))) short s8v;      // same bits, for packing
typedef __attribute__((ext_vector_type(4))) float f4v;
typedef __attribute__((ext_vector_type(16))) float f16v;    // 32x32 MFMA C/D

#define DEV static __device__ __forceinline__

constexpr int NQ = 12544;   // B*H*W = 16*28*28
constexpr int MM = 8192;    // memory bank rows
constexpr int PP = 784;     // H*W
constexpr float EPSF = 1e-12f;

DEV u16 f2bf(float f) {  // RNE f32 -> bf16 (inputs are finite normals)
  u32 u = __float_as_uint(f);
  return (u16)((u + 0x7FFFu + ((u >> 16) & 1u)) >> 16);
}
DEV float bf2f(u16 h) { return __uint_as_float((u32)h << 16); }

DEV void gl2lds16(const u16* g, u16* l) {
  __builtin_amdgcn_global_load_lds(
      (const __attribute__((address_space(1))) unsigned int*)(g),
      (__attribute__((address_space(3))) unsigned int*)(l), 16, 0, 0);
}
DEV void gl2lds4(const float* g, float* l) {
  __builtin_amdgcn_global_load_lds(
      (const __attribute__((address_space(1))) unsigned int*)(g),
      (__attribute__((address_space(3))) unsigned int*)(l), 4, 0, 0);
}

template<int N> DEV void wait_vm() {   // counted vmcnt (T4): literal immediates only
  if constexpr (N == 0) asm volatile("s_waitcnt vmcnt(0)" ::: "memory");
  else if constexpr (N == 2) asm volatile("s_waitcnt vmcnt(2)" ::: "memory");
  else if constexpr (N == 3) asm volatile("s_waitcnt vmcnt(3)" ::: "memory");
  else if constexpr (N == 4) asm volatile("s_waitcnt vmcnt(4)" ::: "memory");
  else if constexpr (N == 6) asm volatile("s_waitcnt vmcnt(6)" ::: "memory");
  else static_assert(N == 0, "unsupported vmcnt");
}

// branchless sorted insert: keep 5 smallest in a0<=..<=a4
DEV void ins5(float v, float& a0, float& a1, float& a2, float& a3, float& a4) {
  float hi;
  hi = fmaxf(v, a0); a0 = fminf(v, a0); v = hi;
  hi = fmaxf(v, a1); a1 = fminf(v, a1); v = hi;
  hi = fmaxf(v, a2); a2 = fminf(v, a2); v = hi;
  hi = fmaxf(v, a3); a3 = fminf(v, a3); v = hi;
  a4 = fminf(v, a4);
}

// ================= fused prep =================
DEV void pack_bf16_dev(const float* __restrict__ x, u16* __restrict__ y, int bid, int tid) {
  int g = bid * 256 + tid;
  const float4* px = (const float4*)x + (size_t)g * 2;
  float4 a = px[0], b = px[1];
  s8v o;
  o[0] = (short)f2bf(a.x); o[1] = (short)f2bf(a.y); o[2] = (short)f2bf(a.z); o[3] = (short)f2bf(a.w);
  o[4] = (short)f2bf(b.x); o[5] = (short)f2bf(b.y); o[6] = (short)f2bf(b.z); o[7] = (short)f2bf(b.w);
  ((s8v*)y)[g] = o;
}

// mem pack: store -2*m (exact bf16 scale) K-MAJOR in global: yT[chunk][row][8]
template<int C>
DEV void pack_mem_dev(const float* __restrict__ x, u16* __restrict__ yT, float* __restrict__ nrm,
                      int bid, int tid) {
  int row = bid * 4 + (tid >> 6), lane = tid & 63;
  constexpr int E = C / 64;
  const float* src = x + (size_t)row * C + lane * E;
  float s = 0.f;
  if constexpr (E == 4) {
    float4 v = *(const float4*)src;
    s = v.x * v.x + v.y * v.y + v.z * v.z + v.w * v.w;
    u32 lo = (u32)f2bf(-2.f * v.x) | ((u32)f2bf(-2.f * v.y) << 16);
    u32 hi = (u32)f2bf(-2.f * v.z) | ((u32)f2bf(-2.f * v.w) << 16);
    size_t di = ((size_t)(lane >> 1) * MM + row) * 8 + (lane & 1) * 4;
    *(uint2*)(yT + di) = make_uint2(lo, hi);
  } else {
    float2 v = *(const float2*)src;
    s = v.x * v.x + v.y * v.y;
    size_t di = ((size_t)(lane >> 2) * MM + row) * 8 + (lane & 3) * 2;
    *(u32*)(yT + di) = (u32)f2bf(-2.f * v.x) | ((u32)f2bf(-2.f * v.y) << 16);
  }
#pragma unroll
  for (int m = 1; m < 64; m <<= 1) s += __shfl_xor(s, m);
  if (lane == 0) nrm[row] = s;
}

template<int C>
DEV void pack_q_dev(const float* __restrict__ q, u16* __restrict__ qfb, int bid, int tid) {
  int g = bid * 256 + tid;
  int n = g % NQ;
  int cc = g / NQ;
  int b = n / PP, p = n % PP;
  int c0 = cc * 8;
  const float* src = q + ((size_t)b * C + c0) * PP + p;
  s8v o;
#pragma unroll
  for (int i = 0; i < 8; ++i) o[i] = (short)f2bf(src[(size_t)i * PP]);
  ((s8v*)qfb)[((size_t)n * C + c0) >> 3] = o;
}

__global__ __launch_bounds__(256) void k_prep(
    const float* __restrict__ q2, const float* __restrict__ q3,
    const float* __restrict__ mem2, const float* __restrict__ mem3,
    const float* __restrict__ icov2, const float* __restrict__ icov3,
    u16* __restrict__ qf2b, u16* __restrict__ qf3b,
    u16* __restrict__ m2t, u16* __restrict__ m3t,
    u16* __restrict__ ic2b, u16* __restrict__ ic3b,
    float* __restrict__ mn2, float* __restrict__ mn3) {
  int bid = blockIdx.x, tid = threadIdx.x;
  if (bid < 2048)       pack_mem_dev<128>(mem2, m2t, mn2, bid, tid);
  else if (bid < 4096)  pack_mem_dev<256>(mem3, m3t, mn3, bid - 2048, tid);
  else if (bid < 4104)  pack_bf16_dev(icov2, ic2b, bid - 4096, tid);
  else if (bid < 4136)  pack_bf16_dev(icov3, ic3b, bid - 4104, tid);
  else if (bid < 4920)  pack_q_dev<128>(q2, qf2b, bid - 4136, tid);
  else                  pack_q_dev<256>(q3, qf3b, bid - 4920, tid);
}

// ================= fused distances + per-row 5 smallest d2' =================
// R11 structure (best measured) + dual top-5 states (halved serial insert chain)
// + free in-kernel q-norms (split==0 blocks hold full q rows in registers).
template<int C, int NSPLIT>
DEV void score_body(const u16* __restrict__ qf, const u16* __restrict__ memT,
                    const float* __restrict__ mn, float* __restrict__ kp,
                    float* __restrict__ qn,
                    int bid2, u16* __restrict__ BsB, float* __restrict__ mnSB, int tid) {
  constexpr int MT = 32, MS = MM / NSPLIT, NT = MS / MT;   // NT = 32 for NSPLIT=8
  constexpr int CHUNKS = C / 8;
  constexpr int SIT = CHUNKS / 16;        // 2 @C=256, 1 @C=128
  constexpr int P = SIT + 1;              // + mn load
  constexpr int BSTRIDE = 8192;           // u16 per LDS buffer (sized for C=256)
  constexpr int QROWS = 8 * 32;
  constexpr int RT = NQ / QROWS;          // 49
  static_assert(NT >= 4, "pipeline needs NT>=4");

  const int wave = tid >> 6, lane = tid & 63;
  const int l31 = lane & 31, kh = lane >> 5;
  const int rt = bid2 % RT, split = bid2 / RT;
  const int row0 = rt * QROWS, mb0 = split * MS;

  // q fragments (B operand; loop-invariant) -> registers, pinned.
  bf8v qv[C / 16];
#pragma unroll
  for (int kk = 0; kk < C / 16; ++kk)
    qv[kk] = *(const bf8v*)(qf + (size_t)(row0 + wave * 32 + l31) * C + kk * 16 + kh * 8);
#pragma unroll
  for (int kk = 0; kk < C / 16; ++kk)
    asm volatile("" : "+v"(qv[kk]));

  // free q-norm: this lane holds half (kh) of q-row (row0+wave*32+l31)
  if (split == 0) {
    float s = 0.f;
#pragma unroll
    for (int kk = 0; kk < C / 16; ++kk)
#pragma unroll
      for (int i = 0; i < 8; ++i) { float v = (float)qv[kk][i]; s = fmaf(v, v, s); }
    s += __shfl_xor(s, 32);   // combine the two K-halves
    if (lane < 32) qn[row0 + wave * 32 + l31] = s;
  }

  auto STAGE = [&](int buf, int t) {   // exactly P vmem ops per wave
    const int mrow0 = mb0 + t * MT;
    u16* Bs = BsB + buf * BSTRIDE;
#pragma unroll
    for (int it = 0; it < SIT; ++it) {
      int cp2 = wave + it * 8;
      gl2lds16(memT + ((size_t)(cp2 * 2 + kh) * MM + mrow0 + l31) * 8,
               Bs + cp2 * 512 + lane * 8);
    }
    gl2lds4(mn + mrow0 + (lane & 31), mnSB + buf * 64 + (lane & 31));   // dup: benign
  };

  // dual top-5 states: A covers g=0,1 ; B covers g=2,3 (independent chains, 2x ILP)
  float a0 = 1e30f, a1 = 1e30f, a2 = 1e30f, a3 = 1e30f, a4 = 1e30f;
  float b0 = 1e30f, b1 = 1e30f, b2 = 1e30f, b3 = 1e30f, b4 = 1e30f;

  auto COMPUTE = [&](int cur) {
    f16v acc;
#pragma unroll
    for (int g = 0; g < 4; ++g) {
      f4v m4 = *(const f4v*)(mnSB + cur * 64 + g * 8 + kh * 4);
      acc[4 * g + 0] = m4[0]; acc[4 * g + 1] = m4[1];
      acc[4 * g + 2] = m4[2]; acc[4 * g + 3] = m4[3];
    }
    const u16* Bb = BsB + cur * BSTRIDE + l31 * 8 + kh * 256;
#pragma unroll
    for (int kk = 0; kk < C / 16; ++kk) {
      bf8v mf = *(const bf8v*)(Bb + kk * 512);
      acc = __builtin_amdgcn_mfma_f32_32x32x16_bf16(mf, qv[kk], acc, 0, 0, 0);
    }
#pragma unroll
    for (int g = 0; g < 2; ++g) {   // -> state A
      float c0 = acc[4 * g + 0], c1 = acc[4 * g + 1];
      float c2 = acc[4 * g + 2], c3 = acc[4 * g + 3];
      float m01 = fminf(fminf(c0, c1), fminf(c2, c3));
      if (m01 < a4) {
        ins5(c0, a0, a1, a2, a3, a4);
        ins5(c1, a0, a1, a2, a3, a4);
        ins5(c2, a0, a1, a2, a3, a4);
        ins5(c3, a0, a1, a2, a3, a4);
      }
    }
#pragma unroll
    for (int g = 2; g < 4; ++g) {   // -> state B
      float c0 = acc[4 * g + 0], c1 = acc[4 * g + 1];
      float c2 = acc[4 * g + 2], c3 = acc[4 * g + 3];
      float m01 = fminf(fminf(c0, c1), fminf(c2, c3));
      if (m01 < b4) {
        ins5(c0, b0, b1, b2, b3, b4);
        ins5(c1, b0, b1, b2, b3, b4);
        ins5(c2, b0, b1, b2, b3, b4);
        ins5(c3, b0, b1, b2, b3, b4);
      }
    }
  };

  STAGE(0, 0); STAGE(1, 1); STAGE(2, 2);   // 3 tiles in flight (3P outstanding)

  for (int t = 0; t < NT - 3; ++t) {
    const int cur = t % 3;
    wait_vm<2 * P>();
    __builtin_amdgcn_sched_barrier(0);
    __builtin_amdgcn_s_barrier();
    __builtin_amdgcn_sched_barrier(0);
    COMPUTE(cur);
    __builtin_amdgcn_sched_barrier(0);
    __builtin_amdgcn_s_barrier();      // all waves done reading Bs[cur]
    __builtin_amdgcn_sched_barrier(0);
    STAGE(cur, t + 3);
  }
  {
    wait_vm<2 * P>();
    __builtin_amdgcn_sched_barrier(0);
    __builtin_amdgcn_s_barrier();
    __builtin_amdgcn_sched_barrier(0);
    COMPUTE((NT - 3) % 3);
    __builtin_amdgcn_sched_barrier(0);
    __builtin_amdgcn_s_barrier();
    wait_vm<P>();
    __builtin_amdgcn_sched_barrier(0);
    __builtin_amdgcn_s_barrier();
    __builtin_amdgcn_sched_barrier(0);
    COMPUTE((NT - 2) % 3);
    __builtin_amdgcn_sched_barrier(0);
    __builtin_amdgcn_s_barrier();
    wait_vm<0>();
    __builtin_amdgcn_sched_barrier(0);
    __builtin_amdgcn_s_barrier();
    __builtin_amdgcn_sched_barrier(0);
    COMPUTE((NT - 1) % 3);
  }

  // merge state B into A, then the 2 lanes holding the same q-col (lane, lane+32)
  ins5(b0, a0, a1, a2, a3, a4);
  ins5(b1, a0, a1, a2, a3, a4);
  ins5(b2, a0, a1, a2, a3, a4);
  ins5(b3, a0, a1, a2, a3, a4);
  ins5(b4, a0, a1, a2, a3, a4);
  {
    float r0 = __shfl_xor(a0, 32), r1 = __shfl_xor(a1, 32), r2 = __shfl_xor(a2, 32),
          r3 = __shfl_xor(a3, 32), r4 = __shfl_xor(a4, 32);
    ins5(r0, a0, a1, a2, a3, a4);
    ins5(r1, a0, a1, a2, a3, a4);
    ins5(r2, a0, a1, a2, a3, a4);
    ins5(r3, a0, a1, a2, a3, a4);
    ins5(r4, a0, a1, a2, a3, a4);
  }
  if (lane < 32) {
    int grow = row0 + wave * 32 + l31;
    float* o = kp + ((size_t)grow * NSPLIT + split) * 5;
    o[0] = a0; o[1] = a1; o[2] = a2; o[3] = a3; o[4] = a4;
  }
}

// fused launcher: even bid -> C=256 (layer 3), odd bid -> C=128 (layer 2)
__global__ __launch_bounds__(512, 4) void k_score_f(
    const u16* __restrict__ qf3, const u16* __restrict__ m3t,
    const float* __restrict__ mn3, float* __restrict__ kp3, float* __restrict__ qn3,
    const u16* __restrict__ qf2, const u16* __restrict__ m2t,
    const float* __restrict__ mn2, float* __restrict__ kp2, float* __restrict__ qn2) {
  __shared__ alignas(16) u16 Bs[3 * 8192];
  __shared__ alignas(16) float mnS[3 * 64];
  int bid = blockIdx.x, tid = threadIdx.x;
  if (bid & 1) score_body<128, 8>(qf2, m2t, mn2, kp2, qn2, bid >> 1, Bs, mnS, tid);
  else         score_body<256, 8>(qf3, m3t, mn3, kp3, qn3, bid >> 1, Bs, mnS, tid);
}

// ================= Mahalanobis only (q-norms now computed in k_score_f) =================
template<int C>
DEV void maha_dev(const u16* __restrict__ qfb, const float* __restrict__ mu,
                  const u16* __restrict__ icovb, float* __restrict__ mh,
                  u16* As, float* muS, int bid, int tid) {
  constexpr int QT = 64, KCH = C / 8;
  int wave = tid >> 6, lane = tid & 63;
  int row0 = bid * QT;

  for (int i = tid; i < C; i += 256) muS[i] = mu[i];
  __syncthreads();
  for (int u = tid; u < QT * KCH; u += 256) {
    int r = u / KCH, cc = u % KCH;
    bf8v v = *(const bf8v*)(qfb + (size_t)(row0 + r) * C + cc * 8);
    s8v d;
#pragma unroll
    for (int i = 0; i < 8; ++i) d[i] = (short)f2bf((float)v[i] - muS[cc * 8 + i]);
    *(s8v*)(As + r * C + ((cc ^ (r & 7)) << 3)) = d;
  }
  __syncthreads();

  int arow = wave * 16 + (lane & 15);
  int kb = lane >> 4;
  float mm[4] = {0.f, 0.f, 0.f, 0.f};
#pragma unroll
  for (int cb = 0; cb < C / 16; ++cb) {
    f4v acc = (f4v){0.f, 0.f, 0.f, 0.f};
    int bcol = cb * 16 + (lane & 15);
#pragma unroll
    for (int kk = 0; kk < C / 32; ++kk) {
      int kc = kk * 4 + kb;
      bf8v a = *(const bf8v*)(As + arow * C + ((kc ^ (arow & 7)) << 3));
      bf8v b = *(const bf8v*)(icovb + (size_t)bcol * C + kc * 8);
      acc = __builtin_amdgcn_mfma_f32_16x16x32_bf16(a, b, acc, 0, 0, 0);
    }
#pragma unroll
    for (int r = 0; r < 4; ++r) {
      int row = wave * 16 + (lane >> 4) * 4 + r;
      int col = cb * 16 + (lane & 15);
      float dv = bf2f(As[row * C + (((col >> 3) ^ (row & 7)) << 3) + (col & 7)]);
      mm[r] += acc[r] * dv;
    }
  }
#pragma unroll
  for (int r = 0; r < 4; ++r) {
    float v = mm[r];
    v += __shfl_xor(v, 1); v += __shfl_xor(v, 2);
    v += __shfl_xor(v, 4); v += __shfl_xor(v, 8);
    if ((lane & 15) == 0)
      mh[row0 + wave * 16 + (lane >> 4) * 4 + r] = sqrtf(fmaxf(v, EPSF));
  }
}

__global__ __launch_bounds__(256) void k_maha(
    const u16* __restrict__ qf2b, const u16* __restrict__ qf3b,
    const float* __restrict__ mean2, const float* __restrict__ mean3,
    const u16* __restrict__ ic2b, const u16* __restrict__ ic3b,
    float* __restrict__ mh2, float* __restrict__ mh3) {
  __shared__ alignas(16) u16 As[64 * 256];
  __shared__ float muS[256];
  int bid = blockIdx.x, tid = threadIdx.x;
  if (bid < 196) maha_dev<128>(qf2b, mean2, ic2b, mh2, As, muS, bid, tid);
  else           maha_dev<256>(qf3b, mean3, ic3b, mh3, As, muS, bid - 196, tid);
}

// ================= combine: merge knn splits (+qn), build maps =================
template<int S>
DEV float knn_merge(const float* kp, int n, float qv) {
  float t0 = 1e30f, t1 = 1e30f, t2 = 1e30f, t3 = 1e30f, t4 = 1e30f;
  const float* p = kp + (size_t)n * S * 5;
#pragma unroll
  for (int i = 0; i < S * 5; ++i) ins5(p[i], t0, t1, t2, t3, t4);
  return 0.2f * (sqrtf(fmaxf(t0 + qv, EPSF)) + sqrtf(fmaxf(t1 + qv, EPSF)) +
                 sqrtf(fmaxf(t2 + qv, EPSF)) + sqrtf(fmaxf(t3 + qv, EPSF)) +
                 sqrtf(fmaxf(t4 + qv, EPSF)));
}

__global__ __launch_bounds__(256) void k_combine(
    const float* __restrict__ kp2, const float* __restrict__ kp3,
    const float* __restrict__ qn2, const float* __restrict__ qn3,
    const float* __restrict__ mh2, const float* __restrict__ mh3,
    float* __restrict__ out) {
  int n = blockIdx.x * 256 + threadIdx.x;
  float m2v = 0.5f * (knn_merge<8>(kp2, n, qn2[n]) + mh2[n]);
  float m3v = 0.5f * (knn_merge<8>(kp3, n, qn3[n]) + mh3[n]);
  out[16 + n] = 0.5f * (m2v + m3v);
  out[16 + NQ + n] = m2v;
  out[16 + 2 * NQ + n] = m3v;
}

// ================= per-image top-10 mean over 784-pixel map =================
__global__ __launch_bounds__(256) void k_top10(const float* __restrict__ comb, float* __restrict__ pred) {
  __shared__ float vals[1024];
  __shared__ float rv[256];
  __shared__ int ri[256];
  __shared__ float ssum;
  int b = blockIdx.x, tid = threadIdx.x;
  for (int i = tid; i < 1024; i += 256) vals[i] = (i < PP) ? comb[b * PP + i] : -1e30f;
  if (tid == 0) ssum = 0.f;
  __syncthreads();
  for (int it = 0; it < 10; ++it) {
    float bv = -1e30f; int bi = 0;
    for (int i = tid; i < 1024; i += 256) { float v = vals[i]; if (v > bv) { bv = v; bi = i; } }
    rv[tid] = bv; ri[tid] = bi;
    __syncthreads();
    for (int s = 128; s; s >>= 1) {
      if (tid < s && rv[tid + s] > rv[tid]) { rv[tid] = rv[tid + s]; ri[tid] = ri[tid + s]; }
      __syncthreads();
    }
    if (tid == 0) { ssum += rv[0]; vals[ri[0]] = -1e30f; }
    __syncthreads();
  }
  if (tid == 0) pred[b] = ssum * 0.1f;
}

extern "C" void kernel_launch(void* const* d_in, const int* in_sizes, int n_in,
                              void* d_out, int out_size, void* d_ws, size_t ws_size,
                              hipStream_t stream) {
  const float* q2    = (const float*)d_in[0];
  const float* q3    = (const float*)d_in[1];
  const float* mem2  = (const float*)d_in[2];
  const float* mem3  = (const float*)d_in[3];
  const float* mean2 = (const float*)d_in[4];
  const float* mean3 = (const float*)d_in[5];
  const float* icov2 = (const float*)d_in[6];
  const float* icov3 = (const float*)d_in[7];
  float* out = (float*)d_out;

  char* w = (char*)d_ws;
  auto alloc = [&](size_t bytes) { void* p = (void*)w; w += (bytes + 255) & ~(size_t)255; return p; };
  u16* qf2b = (u16*)alloc((size_t)NQ * 128 * 2);
  u16* qf3b = (u16*)alloc((size_t)NQ * 256 * 2);
  u16* m2t  = (u16*)alloc((size_t)MM * 128 * 2);
  u16* m3t  = (u16*)alloc((size_t)MM * 256 * 2);
  u16* ic2b = (u16*)alloc((size_t)128 * 128 * 2);
  u16* ic3b = (u16*)alloc((size_t)256 * 256 * 2);
  float* qn2 = (float*)alloc((size_t)NQ * 4);
  float* qn3 = (float*)alloc((size_t)NQ * 4);
  float* mn2 = (float*)alloc((size_t)MM * 4);
  float* mn3 = (float*)alloc((size_t)MM * 4);
  float* kp2 = (float*)alloc((size_t)NQ * 8 * 5 * 4);
  float* kp3 = (float*)alloc((size_t)NQ * 8 * 5 * 4);
  float* mh2 = (float*)alloc((size_t)NQ * 4);
  float* mh3 = (float*)alloc((size_t)NQ * 4);

  k_prep<<<6488, 256, 0, stream>>>(q2, q3, mem2, mem3, icov2, icov3,
                                   qf2b, qf3b, m2t, m3t, ic2b, ic3b, mn2, mn3);

  // fused score (+q-norms): 392 C=256 blocks (even bid) + 392 C=128 blocks (odd bid)
  k_score_f<<<784, 512, 0, stream>>>(qf3b, m3t, mn3, kp3, qn3, qf2b, m2t, mn2, kp2, qn2);

  // maha only: 196 + 196 blocks
  k_maha<<<392, 256, 0, stream>>>(qf2b, qf3b, mean2, mean3, ic2b, ic3b, mh2, mh3);

  k_combine<<<NQ / 256, 256, 0, stream>>>(kp2, kp3, qn2, qn3, mh2, mh3, out);
  k_top10<<<16, 256, 0, stream>>>(out + 16, out);

  (void)in_sizes; (void)n_in; (void)out_size; (void)ws_size;
}

// Round 14
// 211.378 us; speedup vs baseline: 1.1565x; 1.0026x over previous
//
#include <hip/hip_runtime.h>

typedef unsigned short u16;
typedef unsigned int u32;
typedef __attribute__((ext_vector_type(8))) __bf16 bf8v;    // MFMA A/B operand (8 bf16)
typedef __attribute__((ext_vector_type(8))) short s8v;      // same bits, for packing
typedef __attribute__((ext_vector_type(4))) float f4v;
typedef __attribute__((ext_vector_type(16))) float f16v;    // 32x32 MFMA C/D

#define DEV static __device__ __forceinline__

constexpr int NQ = 12544;   // B*H*W = 16*28*28
constexpr int MM = 8192;    // memory bank rows
constexpr int PP = 784;     // H*W
constexpr float EPSF = 1e-12f;

DEV u16 f2bf(float f) {  // RNE f32 -> bf16 (inputs are finite normals)
  u32 u = __float_as_uint(f);
  return (u16)((u + 0x7FFFu + ((u >> 16) & 1u)) >> 16);
}
DEV float bf2f(u16 h) { return __uint_as_float((u32)h << 16); }

DEV void gl2lds16(const u16* g, u16* l) {
  __builtin_amdgcn_global_load_lds(
      (const __attribute__((address_space(1))) unsigned int*)(g),
      (__attribute__((address_space(3))) unsigned int*)(l), 16, 0, 0);
}
DEV void gl2lds4(const float* g, float* l) {
  __builtin_amdgcn_global_load_lds(
      (const __attribute__((address_space(1))) unsigned int*)(g),
      (__attribute__((address_space(3))) unsigned int*)(l), 4, 0, 0);
}

template<int N> DEV void wait_vm() {   // counted vmcnt (T4): literal immediates only
  if constexpr (N == 0) asm volatile("s_waitcnt vmcnt(0)" ::: "memory");
  else if constexpr (N == 3) asm volatile("s_waitcnt vmcnt(3)" ::: "memory");
  else if constexpr (N == 5) asm volatile("s_waitcnt vmcnt(5)" ::: "memory");
  else if constexpr (N == 6) asm volatile("s_waitcnt vmcnt(6)" ::: "memory");
  else if constexpr (N == 10) asm volatile("s_waitcnt vmcnt(10)" ::: "memory");
  else static_assert(N == 0, "unsupported vmcnt");
}

// branchless sorted insert: keep 5 smallest in a0<=..<=a4
DEV void ins5(float v, float& a0, float& a1, float& a2, float& a3, float& a4) {
  float hi;
  hi = fmaxf(v, a0); a0 = fminf(v, a0); v = hi;
  hi = fmaxf(v, a1); a1 = fminf(v, a1); v = hi;
  hi = fmaxf(v, a2); a2 = fminf(v, a2); v = hi;
  hi = fmaxf(v, a3); a3 = fminf(v, a3); v = hi;
  a4 = fminf(v, a4);
}

// ================= fused prep =================
DEV void pack_bf16_dev(const float* __restrict__ x, u16* __restrict__ y, int bid, int tid) {
  int g = bid * 256 + tid;
  const float4* px = (const float4*)x + (size_t)g * 2;
  float4 a = px[0], b = px[1];
  s8v o;
  o[0] = (short)f2bf(a.x); o[1] = (short)f2bf(a.y); o[2] = (short)f2bf(a.z); o[3] = (short)f2bf(a.w);
  o[4] = (short)f2bf(b.x); o[5] = (short)f2bf(b.y); o[6] = (short)f2bf(b.z); o[7] = (short)f2bf(b.w);
  ((s8v*)y)[g] = o;
}

// mem pack: store -2*m (exact bf16 scale) K-MAJOR in global: yT[chunk][row][8]
template<int C>
DEV void pack_mem_dev(const float* __restrict__ x, u16* __restrict__ yT, float* __restrict__ nrm,
                      int bid, int tid) {
  int row = bid * 4 + (tid >> 6), lane = tid & 63;
  constexpr int E = C / 64;
  const float* src = x + (size_t)row * C + lane * E;
  float s = 0.f;
  if constexpr (E == 4) {
    float4 v = *(const float4*)src;
    s = v.x * v.x + v.y * v.y + v.z * v.z + v.w * v.w;
    u32 lo = (u32)f2bf(-2.f * v.x) | ((u32)f2bf(-2.f * v.y) << 16);
    u32 hi = (u32)f2bf(-2.f * v.z) | ((u32)f2bf(-2.f * v.w) << 16);
    size_t di = ((size_t)(lane >> 1) * MM + row) * 8 + (lane & 1) * 4;
    *(uint2*)(yT + di) = make_uint2(lo, hi);
  } else {
    float2 v = *(const float2*)src;
    s = v.x * v.x + v.y * v.y;
    size_t di = ((size_t)(lane >> 2) * MM + row) * 8 + (lane & 3) * 2;
    *(u32*)(yT + di) = (u32)f2bf(-2.f * v.x) | ((u32)f2bf(-2.f * v.y) << 16);
  }
#pragma unroll
  for (int m = 1; m < 64; m <<= 1) s += __shfl_xor(s, m);
  if (lane == 0) nrm[row] = s;
}

template<int C>
DEV void pack_q_dev(const float* __restrict__ q, u16* __restrict__ qfb, int bid, int tid) {
  int g = bid * 256 + tid;
  int n = g % NQ;
  int cc = g / NQ;
  int b = n / PP, p = n % PP;
  int c0 = cc * 8;
  const float* src = q + ((size_t)b * C + c0) * PP + p;
  s8v o;
#pragma unroll
  for (int i = 0; i < 8; ++i) o[i] = (short)f2bf(src[(size_t)i * PP]);
  ((s8v*)qfb)[((size_t)n * C + c0) >> 3] = o;
}

__global__ __launch_bounds__(256) void k_prep(
    const float* __restrict__ q2, const float* __restrict__ q3,
    const float* __restrict__ mem2, const float* __restrict__ mem3,
    const float* __restrict__ icov2, const float* __restrict__ icov3,
    u16* __restrict__ qf2b, u16* __restrict__ qf3b,
    u16* __restrict__ m2t, u16* __restrict__ m3t,
    u16* __restrict__ ic2b, u16* __restrict__ ic3b,
    float* __restrict__ mn2, float* __restrict__ mn3) {
  int bid = blockIdx.x, tid = threadIdx.x;
  if (bid < 2048)       pack_mem_dev<128>(mem2, m2t, mn2, bid, tid);
  else if (bid < 4096)  pack_mem_dev<256>(mem3, m3t, mn3, bid - 2048, tid);
  else if (bid < 4104)  pack_bf16_dev(icov2, ic2b, bid - 4096, tid);
  else if (bid < 4136)  pack_bf16_dev(icov3, ic3b, bid - 4104, tid);
  else if (bid < 4920)  pack_q_dev<128>(q2, qf2b, bid - 4136, tid);
  else                  pack_q_dev<256>(q3, qf3b, bid - 4920, tid);
}

// ================= fused distances + per-row 5 smallest d2' =================
// R13 shell + CG=2: each wave covers 64 q-cols, so ONE A-frag ds_read feeds TWO
// MFMAs (LDS bytes/FLOP halved) with TWO independent acc chains (2x chain ILP).
// 4-wave (256-thr) blocks keep 2 blocks/CU co-resident under the fatter qv.
template<int C, int NSPLIT>
DEV void score_body(const u16* __restrict__ qf, const u16* __restrict__ memT,
                    const float* __restrict__ mn, float* __restrict__ kp,
                    float* __restrict__ qn,
                    int bid2, u16* __restrict__ BsB, float* __restrict__ mnSB, int tid) {
  constexpr int MT = 32, MS = MM / NSPLIT, NT = MS / MT;   // NT = 32
  constexpr int CHUNKS = C / 8;           // 16B chunks per mem row (32 / 16)
  constexpr int PAIRS = CHUNKS / 2;       // K-groups of 16 elems (16 / 8)
  constexpr int SIT = PAIRS / 4;          // gl2lds16 per wave per tile (4 / 2)
  constexpr int P = SIT + 1;              // + mn load (5 / 3)
  constexpr int BSTRIDE = 8192;           // u16 per LDS buffer (16KB, sized for C=256)
  constexpr int QROWS = 4 * 64;           // 4 waves x 64 q-cols = 256
  constexpr int RT = NQ / QROWS;          // 49 exactly
  static_assert(NT >= 4, "pipeline needs NT>=4");

  const int wave = tid >> 6, lane = tid & 63;
  const int l31 = lane & 31, kh = lane >> 5;
  const int rt = bid2 % RT, split = bid2 / RT;   // split-major: same-split blocks cluster (L2)
  const int row0 = rt * QROWS, mb0 = split * MS;

  // q fragments (B operand; loop-invariant) -> registers, pinned. 2 col-groups.
  bf8v qv[2][PAIRS];
#pragma unroll
  for (int cg = 0; cg < 2; ++cg)
#pragma unroll
    for (int kk = 0; kk < PAIRS; ++kk)
      qv[cg][kk] = *(const bf8v*)(qf + (size_t)(row0 + wave * 64 + cg * 32 + l31) * C + kk * 16 + kh * 8);
#pragma unroll
  for (int cg = 0; cg < 2; ++cg)
#pragma unroll
    for (int kk = 0; kk < PAIRS; ++kk)
      asm volatile("" : "+v"(qv[cg][kk]));

  // free q-norm: lane holds K-half kh of q-rows (row0+wave*64+cg*32+l31)
  if (split == 0) {
#pragma unroll
    for (int cg = 0; cg < 2; ++cg) {
      float s = 0.f;
#pragma unroll
      for (int kk = 0; kk < PAIRS; ++kk)
#pragma unroll
        for (int i = 0; i < 8; ++i) { float v = (float)qv[cg][kk][i]; s = fmaf(v, v, s); }
      s += __shfl_xor(s, 32);
      if (lane < 32) qn[row0 + wave * 64 + cg * 32 + l31] = s;
    }
  }

  auto STAGE = [&](int buf, int t) {   // exactly P vmem ops per wave
    const int mrow0 = mb0 + t * MT;
    u16* Bs = BsB + buf * BSTRIDE;
#pragma unroll
    for (int it = 0; it < SIT; ++it) {
      int cp2 = wave + it * 4;
      gl2lds16(memT + ((size_t)(cp2 * 2 + kh) * MM + mrow0 + l31) * 8,
               Bs + cp2 * 512 + lane * 8);
    }
    gl2lds4(mn + mrow0 + (lane & 31), mnSB + buf * 64 + (lane & 31));   // dup: benign
  };

  float t5[2][5];
#pragma unroll
  for (int cg = 0; cg < 2; ++cg)
#pragma unroll
    for (int i = 0; i < 5; ++i) t5[cg][i] = 1e30f;

  auto COMPUTE = [&](int cur) {
    f16v acc[2];
#pragma unroll
    for (int g = 0; g < 4; ++g) {
      f4v m4 = *(const f4v*)(mnSB + cur * 64 + g * 8 + kh * 4);
#pragma unroll
      for (int cg = 0; cg < 2; ++cg) {
        acc[cg][4 * g + 0] = m4[0]; acc[cg][4 * g + 1] = m4[1];
        acc[cg][4 * g + 2] = m4[2]; acc[cg][4 * g + 3] = m4[3];
      }
    }
    const u16* Bb = BsB + cur * BSTRIDE + l31 * 8 + kh * 256;
#pragma unroll
    for (int kk = 0; kk < PAIRS; ++kk) {
      bf8v mf = *(const bf8v*)(Bb + kk * 512);
      acc[0] = __builtin_amdgcn_mfma_f32_32x32x16_bf16(mf, qv[0][kk], acc[0], 0, 0, 0);
      acc[1] = __builtin_amdgcn_mfma_f32_32x32x16_bf16(mf, qv[1][kk], acc[1], 0, 0, 0);
    }
#pragma unroll
    for (int cg = 0; cg < 2; ++cg)
#pragma unroll
      for (int g = 0; g < 4; ++g) {
        float c0 = acc[cg][4 * g + 0], c1 = acc[cg][4 * g + 1];
        float c2 = acc[cg][4 * g + 2], c3 = acc[cg][4 * g + 3];
        float m01 = fminf(fminf(c0, c1), fminf(c2, c3));
        if (m01 < t5[cg][4]) {
          ins5(c0, t5[cg][0], t5[cg][1], t5[cg][2], t5[cg][3], t5[cg][4]);
          ins5(c1, t5[cg][0], t5[cg][1], t5[cg][2], t5[cg][3], t5[cg][4]);
          ins5(c2, t5[cg][0], t5[cg][1], t5[cg][2], t5[cg][3], t5[cg][4]);
          ins5(c3, t5[cg][0], t5[cg][1], t5[cg][2], t5[cg][3], t5[cg][4]);
        }
      }
  };

  STAGE(0, 0); STAGE(1, 1); STAGE(2, 2);   // 3 tiles in flight (3P outstanding)

  for (int t = 0; t < NT - 3; ++t) {
    const int cur = t % 3;
    wait_vm<2 * P>();
    __builtin_amdgcn_sched_barrier(0);
    __builtin_amdgcn_s_barrier();
    __builtin_amdgcn_sched_barrier(0);
    COMPUTE(cur);
    __builtin_amdgcn_sched_barrier(0);
    __builtin_amdgcn_s_barrier();      // all waves done reading Bs[cur]
    __builtin_amdgcn_sched_barrier(0);
    STAGE(cur, t + 3);
  }
  {
    wait_vm<2 * P>();
    __builtin_amdgcn_sched_barrier(0);
    __builtin_amdgcn_s_barrier();
    __builtin_amdgcn_sched_barrier(0);
    COMPUTE((NT - 3) % 3);
    __builtin_amdgcn_sched_barrier(0);
    __builtin_amdgcn_s_barrier();
    wait_vm<P>();
    __builtin_amdgcn_sched_barrier(0);
    __builtin_amdgcn_s_barrier();
    __builtin_amdgcn_sched_barrier(0);
    COMPUTE((NT - 2) % 3);
    __builtin_amdgcn_sched_barrier(0);
    __builtin_amdgcn_s_barrier();
    wait_vm<0>();
    __builtin_amdgcn_sched_barrier(0);
    __builtin_amdgcn_s_barrier();
    __builtin_amdgcn_sched_barrier(0);
    COMPUTE((NT - 1) % 3);
  }

  // per cg: merge the 2 lanes holding the same q-col (lane, lane+32), write
#pragma unroll
  for (int cg = 0; cg < 2; ++cg) {
    float r0 = __shfl_xor(t5[cg][0], 32), r1 = __shfl_xor(t5[cg][1], 32),
          r2 = __shfl_xor(t5[cg][2], 32), r3 = __shfl_xor(t5[cg][3], 32),
          r4 = __shfl_xor(t5[cg][4], 32);
    ins5(r0, t5[cg][0], t5[cg][1], t5[cg][2], t5[cg][3], t5[cg][4]);
    ins5(r1, t5[cg][0], t5[cg][1], t5[cg][2], t5[cg][3], t5[cg][4]);
    ins5(r2, t5[cg][0], t5[cg][1], t5[cg][2], t5[cg][3], t5[cg][4]);
    ins5(r3, t5[cg][0], t5[cg][1], t5[cg][2], t5[cg][3], t5[cg][4]);
    ins5(r4, t5[cg][0], t5[cg][1], t5[cg][2], t5[cg][3], t5[cg][4]);
    if (lane < 32) {
      int grow = row0 + wave * 64 + cg * 32 + l31;
      float* o = kp + ((size_t)grow * NSPLIT + split) * 5;
      o[0] = t5[cg][0]; o[1] = t5[cg][1]; o[2] = t5[cg][2]; o[3] = t5[cg][3]; o[4] = t5[cg][4];
    }
  }
}

// fused launcher: even bid -> C=256 (layer 3), odd bid -> C=128 (layer 2)
__global__ __launch_bounds__(256, 2) void k_score_f(
    const u16* __restrict__ qf3, const u16* __restrict__ m3t,
    const float* __restrict__ mn3, float* __restrict__ kp3, float* __restrict__ qn3,
    const u16* __restrict__ qf2, const u16* __restrict__ m2t,
    const float* __restrict__ mn2, float* __restrict__ kp2, float* __restrict__ qn2) {
  __shared__ alignas(16) u16 Bs[3 * 8192];
  __shared__ alignas(16) float mnS[3 * 64];
  int bid = blockIdx.x, tid = threadIdx.x;
  if (bid & 1) score_body<128, 8>(qf2, m2t, mn2, kp2, qn2, bid >> 1, Bs, mnS, tid);
  else         score_body<256, 8>(qf3, m3t, mn3, kp3, qn3, bid >> 1, Bs, mnS, tid);
}

// ================= Mahalanobis only (q-norms computed in k_score_f) =================
template<int C>
DEV void maha_dev(const u16* __restrict__ qfb, const float* __restrict__ mu,
                  const u16* __restrict__ icovb, float* __restrict__ mh,
                  u16* As, float* muS, int bid, int tid) {
  constexpr int QT = 64, KCH = C / 8;
  int wave = tid >> 6, lane = tid & 63;
  int row0 = bid * QT;

  for (int i = tid; i < C; i += 256) muS[i] = mu[i];
  __syncthreads();
  for (int u = tid; u < QT * KCH; u += 256) {
    int r = u / KCH, cc = u % KCH;
    bf8v v = *(const bf8v*)(qfb + (size_t)(row0 + r) * C + cc * 8);
    s8v d;
#pragma unroll
    for (int i = 0; i < 8; ++i) d[i] = (short)f2bf((float)v[i] - muS[cc * 8 + i]);
    *(s8v*)(As + r * C + ((cc ^ (r & 7)) << 3)) = d;
  }
  __syncthreads();

  int arow = wave * 16 + (lane & 15);
  int kb = lane >> 4;
  float mm[4] = {0.f, 0.f, 0.f, 0.f};
#pragma unroll
  for (int cb = 0; cb < C / 16; ++cb) {
    f4v acc = (f4v){0.f, 0.f, 0.f, 0.f};
    int bcol = cb * 16 + (lane & 15);
#pragma unroll
    for (int kk = 0; kk < C / 32; ++kk) {
      int kc = kk * 4 + kb;
      bf8v a = *(const bf8v*)(As + arow * C + ((kc ^ (arow & 7)) << 3));
      bf8v b = *(const bf8v*)(icovb + (size_t)bcol * C + kc * 8);
      acc = __builtin_amdgcn_mfma_f32_16x16x32_bf16(a, b, acc, 0, 0, 0);
    }
#pragma unroll
    for (int r = 0; r < 4; ++r) {
      int row = wave * 16 + (lane >> 4) * 4 + r;
      int col = cb * 16 + (lane & 15);
      float dv = bf2f(As[row * C + (((col >> 3) ^ (row & 7)) << 3) + (col & 7)]);
      mm[r] += acc[r] * dv;
    }
  }
#pragma unroll
  for (int r = 0; r < 4; ++r) {
    float v = mm[r];
    v += __shfl_xor(v, 1); v += __shfl_xor(v, 2);
    v += __shfl_xor(v, 4); v += __shfl_xor(v, 8);
    if ((lane & 15) == 0)
      mh[row0 + wave * 16 + (lane >> 4) * 4 + r] = sqrtf(fmaxf(v, EPSF));
  }
}

__global__ __launch_bounds__(256) void k_maha(
    const u16* __restrict__ qf2b, const u16* __restrict__ qf3b,
    const float* __restrict__ mean2, const float* __restrict__ mean3,
    const u16* __restrict__ ic2b, const u16* __restrict__ ic3b,
    float* __restrict__ mh2, float* __restrict__ mh3) {
  __shared__ alignas(16) u16 As[64 * 256];
  __shared__ float muS[256];
  int bid = blockIdx.x, tid = threadIdx.x;
  if (bid < 196) maha_dev<128>(qf2b, mean2, ic2b, mh2, As, muS, bid, tid);
  else           maha_dev<256>(qf3b, mean3, ic3b, mh3, As, muS, bid - 196, tid);
}

// ================= combine: merge knn splits (+qn), build maps =================
template<int S>
DEV float knn_merge(const float* kp, int n, float qv) {
  float t0 = 1e30f, t1 = 1e30f, t2 = 1e30f, t3 = 1e30f, t4 = 1e30f;
  const float* p = kp + (size_t)n * S * 5;
#pragma unroll
  for (int i = 0; i < S * 5; ++i) ins5(p[i], t0, t1, t2, t3, t4);
  return 0.2f * (sqrtf(fmaxf(t0 + qv, EPSF)) + sqrtf(fmaxf(t1 + qv, EPSF)) +
                 sqrtf(fmaxf(t2 + qv, EPSF)) + sqrtf(fmaxf(t3 + qv, EPSF)) +
                 sqrtf(fmaxf(t4 + qv, EPSF)));
}

__global__ __launch_bounds__(256) void k_combine(
    const float* __restrict__ kp2, const float* __restrict__ kp3,
    const float* __restrict__ qn2, const float* __restrict__ qn3,
    const float* __restrict__ mh2, const float* __restrict__ mh3,
    float* __restrict__ out) {
  int n = blockIdx.x * 256 + threadIdx.x;
  float m2v = 0.5f * (knn_merge<8>(kp2, n, qn2[n]) + mh2[n]);
  float m3v = 0.5f * (knn_merge<8>(kp3, n, qn3[n]) + mh3[n]);
  out[16 + n] = 0.5f * (m2v + m3v);
  out[16 + NQ + n] = m2v;
  out[16 + 2 * NQ + n] = m3v;
}

// ================= per-image top-10 mean over 784-pixel map =================
__global__ __launch_bounds__(256) void k_top10(const float* __restrict__ comb, float* __restrict__ pred) {
  __shared__ float vals[1024];
  __shared__ float rv[256];
  __shared__ int ri[256];
  __shared__ float ssum;
  int b = blockIdx.x, tid = threadIdx.x;
  for (int i = tid; i < 1024; i += 256) vals[i] = (i < PP) ? comb[b * PP + i] : -1e30f;
  if (tid == 0) ssum = 0.f;
  __syncthreads();
  for (int it = 0; it < 10; ++it) {
    float bv = -1e30f; int bi = 0;
    for (int i = tid; i < 1024; i += 256) { float v = vals[i]; if (v > bv) { bv = v; bi = i; } }
    rv[tid] = bv; ri[tid] = bi;
    __syncthreads();
    for (int s = 128; s; s >>= 1) {
      if (tid < s && rv[tid + s] > rv[tid]) { rv[tid] = rv[tid + s]; ri[tid] = ri[tid + s]; }
      __syncthreads();
    }
    if (tid == 0) { ssum += rv[0]; vals[ri[0]] = -1e30f; }
    __syncthreads();
  }
  if (tid == 0) pred[b] = ssum * 0.1f;
}

extern "C" void kernel_launch(void* const* d_in, const int* in_sizes, int n_in,
                              void* d_out, int out_size, void* d_ws, size_t ws_size,
                              hipStream_t stream) {
  const float* q2    = (const float*)d_in[0];
  const float* q3    = (const float*)d_in[1];
  const float* mem2  = (const float*)d_in[2];
  const float* mem3  = (const float*)d_in[3];
  const float* mean2 = (const float*)d_in[4];
  const float* mean3 = (const float*)d_in[5];
  const float* icov2 = (const float*)d_in[6];
  const float* icov3 = (const float*)d_in[7];
  float* out = (float*)d_out;

  char* w = (char*)d_ws;
  auto alloc = [&](size_t bytes) { void* p = (void*)w; w += (bytes + 255) & ~(size_t)255; return p; };
  u16* qf2b = (u16*)alloc((size_t)NQ * 128 * 2);
  u16* qf3b = (u16*)alloc((size_t)NQ * 256 * 2);
  u16* m2t  = (u16*)alloc((size_t)MM * 128 * 2);
  u16* m3t  = (u16*)alloc((size_t)MM * 256 * 2);
  u16* ic2b = (u16*)alloc((size_t)128 * 128 * 2);
  u16* ic3b = (u16*)alloc((size_t)256 * 256 * 2);
  float* qn2 = (float*)alloc((size_t)NQ * 4);
  float* qn3 = (float*)alloc((size_t)NQ * 4);
  float* mn2 = (float*)alloc((size_t)MM * 4);
  float* mn3 = (float*)alloc((size_t)MM * 4);
  float* kp2 = (float*)alloc((size_t)NQ * 8 * 5 * 4);
  float* kp3 = (float*)alloc((size_t)NQ * 8 * 5 * 4);
  float* mh2 = (float*)alloc((size_t)NQ * 4);
  float* mh3 = (float*)alloc((size_t)NQ * 4);

  k_prep<<<6488, 256, 0, stream>>>(q2, q3, mem2, mem3, icov2, icov3,
                                   qf2b, qf3b, m2t, m3t, ic2b, ic3b, mn2, mn3);

  // fused score (+q-norms): 392 C=256 (even bid) + 392 C=128 (odd bid), 256-thr blocks
  k_score_f<<<784, 256, 0, stream>>>(qf3b, m3t, mn3, kp3, qn3, qf2b, m2t, mn2, kp2, qn2);

  k_maha<<<392, 256, 0, stream>>>(qf2b, qf3b, mean2, mean3, ic2b, ic3b, mh2, mh3);

  k_combine<<<NQ / 256, 256, 0, stream>>>(kp2, kp3, qn2, qn3, mh2, mh3, out);
  k_top10<<<16, 256, 0, stream>>>(out + 16, out);

  (void)in_sizes; (void)n_in; (void)out_size; (void)ws_size;
}